// Round 7
// baseline (181.082 us; speedup 1.0000x reference)
//
#include <hip/hip_runtime.h>
#include <math.h>

#define BQ 16
#define TT 1024
#define DD 300
#define KK 11
#define ND4 75      // DD/4
#define KPAD 320    // fp8 bytes per row (K padded to 320)
#define NCH 4       // chunks per pair; wave = 64 doc tokens = 4 tiles

typedef unsigned short u16;
typedef unsigned char u8;
typedef long long i64;
typedef float f32x4 __attribute__((ext_vector_type(4)));
typedef long long i64x2 __attribute__((ext_vector_type(2)));

// ---- manual RNE float -> OCP e4m3fn (values here are |v| <= 1, no sat needed)
__device__ __forceinline__ unsigned f2e4m3(float f) {
    unsigned u = __float_as_uint(f);
    unsigned s = (u >> 24) & 0x80u;
    float a = fabsf(f);
    unsigned code;
    if (a < 0.015625f) {                 // below 2^-6: subnormal, quantum 2^-9
        code = (unsigned)(int)rintf(a * 512.0f);
    } else {
        unsigned au = u & 0x7fffffffu;
        au += 0x7ffffu + ((au >> 20) & 1u);        // RNE at bit 20
        int e32 = (int)(au >> 23) - 127;
        code = ((unsigned)(e32 + 7) << 3) | ((au >> 20) & 7u);
    }
    return s | code;
}

// ---------------- Kernel A: normalize emb -> fp8 table, PERMUTED rows ----------------
// Row layout: byte for k (k=ks*32+quad*8+j) stored at quad*80 + ks*8 + j.
// A lane's two consecutive ks-fragments are then 16B contiguous.
__global__ __launch_bounds__(256) void knrm_norm_table(
    const float* __restrict__ emb, u8* __restrict__ table, int V)
{
    const int tid = threadIdx.x;
    const int sub = tid & 15;
    const int row = blockIdx.x * 16 + (tid >> 4);
    if (row >= V) return;

    const float4* __restrict__ src = (const float4*)(emb + (size_t)row * DD);
    float4 v[5];
    float ssq = 0.f;
    #pragma unroll
    for (int it = 0; it < 5; ++it) {
        int j = sub + 16 * it;
        if (j < ND4) {
            v[it] = src[j];
            ssq += v[it].x * v[it].x + v[it].y * v[it].y
                 + v[it].z * v[it].z + v[it].w * v[it].w;
        } else {
            v[it] = make_float4(0.f, 0.f, 0.f, 0.f);
        }
    }
    #pragma unroll
    for (int off = 8; off; off >>= 1) ssq += __shfl_xor(ssq, off, 16);
    const float inv = (row == 0) ? 0.f : 1.f / (sqrtf(ssq) + 1e-9f);

    unsigned* __restrict__ dst = (unsigned*)(table + (size_t)row * KPAD);
    #pragma unroll
    for (int it = 0; it < 5; ++it) {
        int j = sub + 16 * it;      // source dword index 0..79 (k = 4j..4j+3)
        unsigned w = f2e4m3(v[it].x * inv)
                   | (f2e4m3(v[it].y * inv) << 8)
                   | (f2e4m3(v[it].z * inv) << 16)
                   | (f2e4m3(v[it].w * inv) << 24);
        int quad = (j >> 1) & 3;
        int ks   = j >> 3;
        int d    = quad * 20 + ks * 2 + (j & 1);   // permuted dword index
        dst[d] = w;
    }
}

// ---------------- Kernel B: fp8 MFMA sim + RBF partials ----------------
// grid: pair(512) x chunk(4); block 256 = 4 waves; wave = 64 doc tokens = 4 tiles.
// Register double-buffer: tile t+1's 5x16B loads issue before tile t's compute.
__global__ __launch_bounds__(256, 4) void knrm_mfma(
    const int* __restrict__ posdoc, const int* __restrict__ negdoc,
    const int* __restrict__ query,
    const u8* __restrict__ table,
    const float* __restrict__ mus, const float* __restrict__ sigmas,
    float* __restrict__ part)
{
    __shared__ float red[4][BQ][12];

    const int bid   = blockIdx.x;
    const int pair  = bid >> 2;
    const int chunk = bid & 3;
    const int bb    = pair >> 1;
    const int* __restrict__ doc = (pair & 1) ? negdoc : posdoc;
    const int tid  = threadIdx.x;
    const int lane = tid & 63;
    const int wave = tid >> 6;
    const int quad = lane >> 4;
    const int m    = lane & 15;

    // doc tokens first (longest dependence chain)
    const int tbase = bb * TT + chunk * 256 + wave * 64 + m;
    int toks[4];
    #pragma unroll
    for (int t = 0; t < 4; ++t) toks[t] = doc[tbase + t * 16];
    const i64x2* __restrict__ bp[4];
    #pragma unroll
    for (int t = 0; t < 4; ++t)
        bp[t] = (const i64x2*)(table + (size_t)toks[t] * KPAD + quad * 80);

    // A-fragments: query row m, permuted layout -> 5 x 16B contiguous
    const int qtok = query[bb * BQ + m];
    const i64x2* __restrict__ ap = (const i64x2*)(table + (size_t)qtok * KPAD + quad * 80);
    i64x2 afr[5];
    #pragma unroll
    for (int g = 0; g < 5; ++g) afr[g] = ap[g];

    float muk[10], ck[10];
    #pragma unroll
    for (int k = 0; k < 10; ++k) {
        muk[k] = mus[k];
        float sg = sigmas[k];
        ck[k] = -0.72134752f / (sg * sg);    // -0.5*log2(e)/sg^2
    }

    float vacc[12][4];
    #pragma unroll
    for (int v = 0; v < 12; ++v)
        #pragma unroll
        for (int r = 0; r < 4; ++r) vacc[v][r] = 0.f;

    i64x2 bbuf[2][5];
    #pragma unroll
    for (int g = 0; g < 5; ++g) bbuf[0][g] = bp[0][g];

    #pragma unroll
    for (int t = 0; t < 4; ++t) {
        const int cur = t & 1;
        if (t < 3) {
            #pragma unroll
            for (int g = 0; g < 5; ++g) bbuf[cur ^ 1][g] = bp[t + 1][g];
        }
        f32x4 acc = {0.f, 0.f, 0.f, 0.f};
        #pragma unroll
        for (int g = 0; g < 5; ++g) {
            acc = __builtin_amdgcn_mfma_f32_16x16x32_fp8_fp8(afr[g].x, bbuf[cur][g].x, acc, 0, 0, 0);
            acc = __builtin_amdgcn_mfma_f32_16x16x32_fp8_fp8(afr[g].y, bbuf[cur][g].y, acc, 0, 0, 0);
        }
        // RBF accumulate. C/D: col = m (doc token), row q = quad*4 + r.
        #pragma unroll
        for (int r = 0; r < 4; ++r) {
            float s = acc[r];
            vacc[11][r] += s;                              // simsum (qmask)
            vacc[10][r] += (s > 0.9f ? 1.f : 0.f);         // exact-match kernel
            #pragma unroll
            for (int k = 0; k < 10; ++k) {
                float d = s - muk[k];
                vacc[k][r] += __builtin_amdgcn_exp2f(ck[k] * d * d);
            }
        }
    }

    // one cross-lane reduction per wave
    #pragma unroll
    for (int r = 0; r < 4; ++r) {
        #pragma unroll
        for (int off = 8; off; off >>= 1)
            #pragma unroll
            for (int v = 0; v < 12; ++v)
                vacc[v][r] += __shfl_down(vacc[v][r], off, 16);
        if (m == 0) {
            int q = quad * 4 + r;
            #pragma unroll
            for (int v = 0; v < 12; ++v) red[wave][q][v] = vacc[v][r];
        }
    }
    __syncthreads();

    if (tid < 192) {
        int v = tid >> 4, q = tid & 15;
        float sum = red[0][q][v] + red[1][q][v] + red[2][q][v] + red[3][q][v];
        part[((size_t)bid * 12 + v) * BQ + q] = sum;
    }
}

// ---------------- Fallback fp32 partial kernel (round-2 path) ----------------
__global__ __launch_bounds__(256) void knrm_partial(
    const int* __restrict__ posdoc, const int* __restrict__ negdoc,
    const int* __restrict__ query,
    const float* __restrict__ emb,
    const float* __restrict__ mus, const float* __restrict__ sigmas,
    float* __restrict__ ws)
{
    __shared__ __align__(16) float qs[BQ * DD];
    __shared__ float qscale[BQ];

    const int bid   = blockIdx.x;
    const int pair  = bid >> 2;
    const int chunk = bid & 3;
    const int bb    = pair >> 1;
    const int sel   = pair & 1;
    const int* __restrict__ doc = sel ? negdoc : posdoc;
    const int tid  = threadIdx.x;
    const int lane = tid & 63;
    const int wave = tid >> 6;

    float4* qs4 = (float4*)qs;
    for (int idx = tid; idx < BQ * ND4; idx += 256) {
        int q   = idx / ND4;
        int c   = idx - q * ND4;
        int tok = query[bb * BQ + q];
        qs4[idx] = ((const float4*)(emb + (size_t)tok * DD))[c];
    }
    __syncthreads();
    {
        int q = tid >> 4, sub = tid & 15;
        float ssq = 0.f;
        for (int i = sub; i < DD; i += 16) { float v = qs[q * DD + i]; ssq += v * v; }
        #pragma unroll
        for (int off = 8; off; off >>= 1) ssq += __shfl_down(ssq, off, 16);
        if (sub == 0) {
            int tok = query[bb * BQ + q];
            qscale[q] = (tok == 0) ? 0.f : 1.f / (sqrtf(ssq) + 1e-9f);
        }
    }
    __syncthreads();
    for (int idx = tid; idx < BQ * ND4; idx += 256) {
        int q = idx / ND4;
        float sc = qscale[q];
        float4 v = qs4[idx];
        v.x *= sc; v.y *= sc; v.z *= sc; v.w *= sc;
        qs4[idx] = v;
    }
    __syncthreads();

    const int tok = doc[bb * TT + chunk * 256 + tid];
    const float4* __restrict__ rowp = (const float4*)(emb + (size_t)tok * DD);
    float acc[BQ];
    #pragma unroll
    for (int q = 0; q < BQ; ++q) acc[q] = 0.f;
    float dss = 0.f;
    #pragma unroll 5
    for (int d4 = 0; d4 < ND4; ++d4) {
        float4 dv = rowp[d4];
        dss += dv.x * dv.x + dv.y * dv.y + dv.z * dv.z + dv.w * dv.w;
        #pragma unroll
        for (int q = 0; q < BQ; ++q) {
            float4 qv = qs4[q * ND4 + d4];
            acc[q] += dv.x * qv.x + dv.y * qv.y + dv.z * qv.z + dv.w * qv.w;
        }
    }
    const float invd = (tok == 0) ? 0.f : 1.f / (sqrtf(dss) + 1e-9f);

    float muk[KK], ck[KK];
    #pragma unroll
    for (int k = 0; k < KK; ++k) {
        muk[k] = mus[k];
        float sg = sigmas[k];
        ck[k] = -0.72134752f / (sg * sg);
    }
    __syncthreads();
    float* red = qs;
    const int grp = wave * 4 + (lane >> 4);
    const bool wr = (lane & 15) == 0;
    for (int q = 0; q < BQ; ++q) {
        float s = acc[q] * invd;
        float vals[12];
        vals[11] = s;
        #pragma unroll
        for (int k = 0; k < KK; ++k) {
            float d = s - muk[k];
            vals[k] = __builtin_amdgcn_exp2f(ck[k] * d * d);
        }
        #pragma unroll
        for (int off = 8; off; off >>= 1)
            #pragma unroll
            for (int v = 0; v < 12; ++v)
                vals[v] += __shfl_down(vals[v], off, 16);
        if (wr) {
            #pragma unroll
            for (int v = 0; v < 12; ++v) red[(grp * BQ + q) * 12 + v] = vals[v];
        }
    }
    __syncthreads();
    if (tid < 192) {
        int v = tid >> 4, q = tid & 15;
        float sum = 0.f;
        #pragma unroll
        for (int g = 0; g < 16; ++g) sum += red[(g * BQ + q) * 12 + v];
        ws[((size_t)(pair * 4 + chunk) * 12 + v) * BQ + q] = sum;
    }
}

// ---------------- Final: combine chunks, log+qmask, dot with W ----------------
__global__ __launch_bounds__(192) void knrm_final(
    const float* __restrict__ part,
    const float* __restrict__ Wv, const float* __restrict__ bv,
    float* __restrict__ out, int nchunk)
{
    __shared__ float dock[12 * BQ];
    __shared__ float lsum[KK];
    const int pair = blockIdx.x;
    const int tid  = threadIdx.x;
    {
        int v = tid >> 4, q = tid & 15;
        float sum = 0.f;
        for (int c = 0; c < nchunk; ++c)
            sum += part[((size_t)(pair * nchunk + c) * 12 + v) * BQ + q];
        dock[v * BQ + q] = sum;
    }
    __syncthreads();
    if (tid < 176) {
        int k = tid >> 4, q = tid & 15;
        float qm = dock[11 * BQ + q];
        float lv = (qm != 0.0f) ? logf(dock[k * BQ + q] + 1e-6f) : 0.f;
        #pragma unroll
        for (int off = 8; off; off >>= 1) lv += __shfl_down(lv, off, 16);
        if (q == 0) lsum[k] = lv;
    }
    __syncthreads();
    if (tid == 0) {
        float sc = bv[0];
        #pragma unroll
        for (int k = 0; k < KK; ++k) sc += lsum[k] * Wv[k];
        out[pair] = sc;
    }
}

extern "C" void kernel_launch(void* const* d_in, const int* in_sizes, int n_in,
                              void* d_out, int out_size, void* d_ws, size_t ws_size,
                              hipStream_t stream) {
    const int*   posdoc = (const int*)  d_in[0];
    const int*   negdoc = (const int*)  d_in[1];
    const int*   query  = (const int*)  d_in[2];
    const float* emb    = (const float*)d_in[4];
    const float* mus    = (const float*)d_in[5];
    const float* sigmas = (const float*)d_in[6];
    const float* Wv     = (const float*)d_in[7];
    const float* bv     = (const float*)d_in[8];
    float* out = (float*)d_out;

    const int V = in_sizes[4] / DD;          // 50000
    const size_t table_bytes = (size_t)V * KPAD;                     // 16 MB fp8
    const size_t part_bytes  = (size_t)512 * NCH * 12 * BQ * sizeof(float);

    if (ws_size >= table_bytes + part_bytes) {
        u8*    table = (u8*)d_ws;
        float* part  = (float*)((char*)d_ws + table_bytes);
        knrm_norm_table<<<dim3((V + 15) / 16), dim3(256), 0, stream>>>(emb, table, V);
        knrm_mfma<<<dim3(512 * NCH), dim3(256), 0, stream>>>(
            posdoc, negdoc, query, table, mus, sigmas, part);
        knrm_final<<<dim3(512), dim3(192), 0, stream>>>(part, Wv, bv, out, NCH);
    } else {
        float* part = (float*)d_ws;
        knrm_partial<<<dim3(512 * 4), dim3(256), 0, stream>>>(
            posdoc, negdoc, query, emb, mus, sigmas, part);
        knrm_final<<<dim3(512), dim3(192), 0, stream>>>(part, Wv, bv, out, 4);
    }
}

// Round 8
// 151.084 us; speedup vs baseline: 1.1986x; 1.1986x over previous
//
#include <hip/hip_runtime.h>
#include <math.h>

#define BQ 16
#define TT 1024
#define DD 300
#define KK 11
#define ND4 75      // DD/4
#define KPAD 320    // fp8 bytes per row (K padded to 320), layout [ks*32 + quad*8 + j]
#define NCH 4       // chunks per pair; wave = 64 doc tokens = 4 tiles

typedef unsigned short u16;
typedef unsigned char u8;
typedef long long i64;
typedef float f32x4 __attribute__((ext_vector_type(4)));

// ---- manual RNE float -> OCP e4m3fn (values here are |v| <= 1, no sat needed)
__device__ __forceinline__ unsigned f2e4m3(float f) {
    unsigned u = __float_as_uint(f);
    unsigned s = (u >> 24) & 0x80u;
    float a = fabsf(f);
    unsigned code;
    if (a < 0.015625f) {                 // below 2^-6: subnormal, quantum 2^-9
        code = (unsigned)(int)rintf(a * 512.0f);
    } else {
        unsigned au = u & 0x7fffffffu;
        au += 0x7ffffu + ((au >> 20) & 1u);        // RNE at bit 20
        int e32 = (int)(au >> 23) - 127;
        code = ((unsigned)(e32 + 7) << 3) | ((au >> 20) & 7u);
    }
    return s | code;
}

// ---- asm gather: 8B load with immediate offset; volatile -> scheduler can't sink it
template<int OFF>
__device__ __forceinline__ void gload8(i64& dst, const u8* p) {
    asm volatile("global_load_dwordx2 %0, %1, off offset:%2"
                 : "=v"(dst) : "v"(p), "i"(OFF));
}

#define ISSUE_TILE(B, P)                                                    \
    gload8<0>((B)[0], P);   gload8<32>((B)[1], P);  gload8<64>((B)[2], P);  \
    gload8<96>((B)[3], P);  gload8<128>((B)[4], P); gload8<160>((B)[5], P); \
    gload8<192>((B)[6], P); gload8<224>((B)[7], P); gload8<256>((B)[8], P); \
    gload8<288>((B)[9], P);

// wait until <=N vmem outstanding; ties tile B so MFMAs can't move above the wait
#define TILE_WAIT(NSTR, B)                                                  \
    asm volatile("s_waitcnt vmcnt(" NSTR ")"                                \
        : "+v"((B)[0]), "+v"((B)[1]), "+v"((B)[2]), "+v"((B)[3]),           \
          "+v"((B)[4]), "+v"((B)[5]), "+v"((B)[6]), "+v"((B)[7]),           \
          "+v"((B)[8]), "+v"((B)[9]))

// ---------------- Kernel A: normalize emb -> fp8 table [V][KPAD] ----------------
// One wave per row: 75 lanes read float4 (coalesced 1200B), butterfly, 80-dword write.
__global__ __launch_bounds__(256) void knrm_norm_table(
    const float* __restrict__ emb, u8* __restrict__ table, int V)
{
    const int w    = (blockIdx.x * 256 + threadIdx.x) >> 6;   // row
    const int lane = threadIdx.x & 63;
    if (w >= V) return;

    const float4* __restrict__ src = (const float4*)(emb + (size_t)w * DD);
    float4 v = make_float4(0.f, 0.f, 0.f, 0.f);
    float4 v2 = v;
    if (lane < ND4) v = src[lane];                 // lanes 0..63 -> dwords 0..63
    if (lane < ND4 - 64) v2 = src[64 + lane];      // lanes 0..10 -> dwords 64..74
    float ssq = v.x * v.x + v.y * v.y + v.z * v.z + v.w * v.w
              + v2.x * v2.x + v2.y * v2.y + v2.z * v2.z + v2.w * v2.w;
    #pragma unroll
    for (int off = 32; off; off >>= 1) ssq += __shfl_xor(ssq, off);
    const float inv = (w == 0) ? 0.f : 1.f / (sqrtf(ssq) + 1e-9f);

    unsigned* __restrict__ dst = (unsigned*)(table + (size_t)w * KPAD);  // 80 dwords
    unsigned p = f2e4m3(v.x * inv) | (f2e4m3(v.y * inv) << 8)
               | (f2e4m3(v.z * inv) << 16) | (f2e4m3(v.w * inv) << 24);
    dst[lane] = (lane < ND4) ? p : 0u;             // dwords 0..63
    if (lane < 16) {                               // dwords 64..79 (75..79 = pad)
        unsigned p2 = f2e4m3(v2.x * inv) | (f2e4m3(v2.y * inv) << 8)
                    | (f2e4m3(v2.z * inv) << 16) | (f2e4m3(v2.w * inv) << 24);
        dst[64 + lane] = (lane < ND4 - 64) ? p2 : 0u;
    }
}

// ---------------- Kernel B: fp8 MFMA sim + RBF partials ----------------
// grid: pair(512) x chunk(4); block 256 = 4 waves; wave = 64 doc tokens = 4 tiles.
// Hand-scheduled gather pipeline: 2 tiles (20 loads) in flight via asm + vmcnt.
__global__ __launch_bounds__(256, 3) void knrm_mfma(
    const int* __restrict__ posdoc, const int* __restrict__ negdoc,
    const int* __restrict__ query,
    const u8* __restrict__ table,
    const float* __restrict__ mus, const float* __restrict__ sigmas,
    float* __restrict__ part)
{
    __shared__ float red[4][BQ][12];

    const int bid   = blockIdx.x;
    const int pair  = bid >> 2;
    const int chunk = bid & 3;
    const int bb    = pair >> 1;
    const int* __restrict__ doc = (pair & 1) ? negdoc : posdoc;
    const int tid  = threadIdx.x;
    const int lane = tid & 63;
    const int wave = tid >> 6;
    const int quad = lane >> 4;
    const int m    = lane & 15;

    // doc tokens + row pointers (compiler-visible loads, drained before asm pipeline)
    const int tbase = bb * TT + chunk * 256 + wave * 64 + m;
    int toks[4];
    #pragma unroll
    for (int t = 0; t < 4; ++t) toks[t] = doc[tbase + t * 16];
    const u8* bp0 = table + (size_t)toks[0] * KPAD + quad * 8;
    const u8* bp1 = table + (size_t)toks[1] * KPAD + quad * 8;
    const u8* bp2 = table + (size_t)toks[2] * KPAD + quad * 8;
    const u8* bp3 = table + (size_t)toks[3] * KPAD + quad * 8;

    // A-fragments: query row m (10 x 8B in registers)
    const int qtok = query[bb * BQ + m];
    const i64* __restrict__ ap = (const i64*)(table + (size_t)qtok * KPAD + quad * 8);
    i64 afr[10];
    #pragma unroll
    for (int ks = 0; ks < 10; ++ks) afr[ks] = ap[ks * 4];

    float muk[10], ck[10];
    #pragma unroll
    for (int k = 0; k < 10; ++k) {
        muk[k] = mus[k];
        float sg = sigmas[k];
        ck[k] = -0.72134752f / (sg * sg);    // -0.5*log2(e)/sg^2
    }

    float vacc[12][4];
    #pragma unroll
    for (int v = 0; v < 12; ++v)
        #pragma unroll
        for (int r = 0; r < 4; ++r) vacc[v][r] = 0.f;

    // sync point: drain ALL compiler-issued vmem (ties afr -> its waits emitted here).
    // After this, vmcnt is exclusively owned by the asm pipeline below.
    asm volatile("s_waitcnt vmcnt(0)"
        : "+v"(afr[0]), "+v"(afr[1]), "+v"(afr[2]), "+v"(afr[3]), "+v"(afr[4]),
          "+v"(afr[5]), "+v"(afr[6]), "+v"(afr[7]), "+v"(afr[8]), "+v"(afr[9]));

    i64 ba[10], bbuf[10];
    ISSUE_TILE(ba, bp0);       // out = 10
    ISSUE_TILE(bbuf, bp1);     // out = 20

    #define COMPUTE_TILE(B)                                                        \
    {                                                                              \
        f32x4 acc = {0.f, 0.f, 0.f, 0.f};                                          \
        _Pragma("unroll")                                                          \
        for (int g = 0; g < 10; ++g)                                               \
            acc = __builtin_amdgcn_mfma_f32_16x16x32_fp8_fp8(afr[g], (B)[g], acc, 0, 0, 0); \
        _Pragma("unroll")                                                          \
        for (int r = 0; r < 4; ++r) {                                              \
            float s = acc[r];                                                      \
            vacc[11][r] += s;                                                      \
            vacc[10][r] += (s > 0.9f ? 1.f : 0.f);                                 \
            _Pragma("unroll")                                                      \
            for (int k = 0; k < 10; ++k) {                                         \
                float d = s - muk[k];                                              \
                vacc[k][r] += __builtin_amdgcn_exp2f(ck[k] * d * d);               \
            }                                                                      \
        }                                                                          \
    }

    TILE_WAIT("10", ba);    // T0 ready (out 20->10)
    COMPUTE_TILE(ba);
    ISSUE_TILE(ba, bp2);    // out = 20
    TILE_WAIT("10", bbuf);  // T1 ready
    COMPUTE_TILE(bbuf);
    ISSUE_TILE(bbuf, bp3);  // out = 20
    TILE_WAIT("10", ba);    // T2 ready
    COMPUTE_TILE(ba);
    TILE_WAIT("0", bbuf);   // T3 ready
    COMPUTE_TILE(bbuf);
    #undef COMPUTE_TILE

    // one cross-lane reduction per wave
    #pragma unroll
    for (int r = 0; r < 4; ++r) {
        #pragma unroll
        for (int off = 8; off; off >>= 1)
            #pragma unroll
            for (int v = 0; v < 12; ++v)
                vacc[v][r] += __shfl_down(vacc[v][r], off, 16);
        if (m == 0) {
            int q = quad * 4 + r;
            #pragma unroll
            for (int v = 0; v < 12; ++v) red[wave][q][v] = vacc[v][r];
        }
    }
    __syncthreads();

    if (tid < 192) {
        int v = tid >> 4, q = tid & 15;
        float sum = red[0][q][v] + red[1][q][v] + red[2][q][v] + red[3][q][v];
        part[((size_t)bid * 12 + v) * BQ + q] = sum;
    }
}

// ---------------- Fallback fp32 partial kernel (round-2 path) ----------------
__global__ __launch_bounds__(256) void knrm_partial(
    const int* __restrict__ posdoc, const int* __restrict__ negdoc,
    const int* __restrict__ query,
    const float* __restrict__ emb,
    const float* __restrict__ mus, const float* __restrict__ sigmas,
    float* __restrict__ ws)
{
    __shared__ __align__(16) float qs[BQ * DD];
    __shared__ float qscale[BQ];

    const int bid   = blockIdx.x;
    const int pair  = bid >> 2;
    const int chunk = bid & 3;
    const int bb    = pair >> 1;
    const int sel   = pair & 1;
    const int* __restrict__ doc = sel ? negdoc : posdoc;
    const int tid  = threadIdx.x;
    const int lane = tid & 63;
    const int wave = tid >> 6;

    float4* qs4 = (float4*)qs;
    for (int idx = tid; idx < BQ * ND4; idx += 256) {
        int q   = idx / ND4;
        int c   = idx - q * ND4;
        int tok = query[bb * BQ + q];
        qs4[idx] = ((const float4*)(emb + (size_t)tok * DD))[c];
    }
    __syncthreads();
    {
        int q = tid >> 4, sub = tid & 15;
        float ssq = 0.f;
        for (int i = sub; i < DD; i += 16) { float v = qs[q * DD + i]; ssq += v * v; }
        #pragma unroll
        for (int off = 8; off; off >>= 1) ssq += __shfl_down(ssq, off, 16);
        if (sub == 0) {
            int tok = query[bb * BQ + q];
            qscale[q] = (tok == 0) ? 0.f : 1.f / (sqrtf(ssq) + 1e-9f);
        }
    }
    __syncthreads();
    for (int idx = tid; idx < BQ * ND4; idx += 256) {
        int q = idx / ND4;
        float sc = qscale[q];
        float4 v = qs4[idx];
        v.x *= sc; v.y *= sc; v.z *= sc; v.w *= sc;
        qs4[idx] = v;
    }
    __syncthreads();

    const int tok = doc[bb * TT + chunk * 256 + tid];
    const float4* __restrict__ rowp = (const float4*)(emb + (size_t)tok * DD);
    float acc[BQ];
    #pragma unroll
    for (int q = 0; q < BQ; ++q) acc[q] = 0.f;
    float dss = 0.f;
    #pragma unroll 5
    for (int d4 = 0; d4 < ND4; ++d4) {
        float4 dv = rowp[d4];
        dss += dv.x * dv.x + dv.y * dv.y + dv.z * dv.z + dv.w * dv.w;
        #pragma unroll
        for (int q = 0; q < BQ; ++q) {
            float4 qv = qs4[q * ND4 + d4];
            acc[q] += dv.x * qv.x + dv.y * qv.y + dv.z * qv.z + dv.w * qv.w;
        }
    }
    const float invd = (tok == 0) ? 0.f : 1.f / (sqrtf(dss) + 1e-9f);

    float muk[KK], ck[KK];
    #pragma unroll
    for (int k = 0; k < KK; ++k) {
        muk[k] = mus[k];
        float sg = sigmas[k];
        ck[k] = -0.72134752f / (sg * sg);
    }
    __syncthreads();
    float* red = qs;
    const int grp = wave * 4 + (lane >> 4);
    const bool wr = (lane & 15) == 0;
    for (int q = 0; q < BQ; ++q) {
        float s = acc[q] * invd;
        float vals[12];
        vals[11] = s;
        #pragma unroll
        for (int k = 0; k < KK; ++k) {
            float d = s - muk[k];
            vals[k] = __builtin_amdgcn_exp2f(ck[k] * d * d);
        }
        #pragma unroll
        for (int off = 8; off; off >>= 1)
            #pragma unroll
            for (int v = 0; v < 12; ++v)
                vals[v] += __shfl_down(vals[v], off, 16);
        if (wr) {
            #pragma unroll
            for (int v = 0; v < 12; ++v) red[(grp * BQ + q) * 12 + v] = vals[v];
        }
    }
    __syncthreads();
    if (tid < 192) {
        int v = tid >> 4, q = tid & 15;
        float sum = 0.f;
        #pragma unroll
        for (int g = 0; g < 16; ++g) sum += red[(g * BQ + q) * 12 + v];
        ws[((size_t)(pair * 4 + chunk) * 12 + v) * BQ + q] = sum;
    }
}

// ---------------- Final: combine chunks, log+qmask, dot with W ----------------
__global__ __launch_bounds__(192) void knrm_final(
    const float* __restrict__ part,
    const float* __restrict__ Wv, const float* __restrict__ bv,
    float* __restrict__ out, int nchunk)
{
    __shared__ float dock[12 * BQ];
    __shared__ float lsum[KK];
    const int pair = blockIdx.x;
    const int tid  = threadIdx.x;
    {
        int v = tid >> 4, q = tid & 15;
        float sum = 0.f;
        for (int c = 0; c < nchunk; ++c)
            sum += part[((size_t)(pair * nchunk + c) * 12 + v) * BQ + q];
        dock[v * BQ + q] = sum;
    }
    __syncthreads();
    if (tid < 176) {
        int k = tid >> 4, q = tid & 15;
        float qm = dock[11 * BQ + q];
        float lv = (qm != 0.0f) ? logf(dock[k * BQ + q] + 1e-6f) : 0.f;
        #pragma unroll
        for (int off = 8; off; off >>= 1) lv += __shfl_down(lv, off, 16);
        if (q == 0) lsum[k] = lv;
    }
    __syncthreads();
    if (tid == 0) {
        float sc = bv[0];
        #pragma unroll
        for (int k = 0; k < KK; ++k) sc += lsum[k] * Wv[k];
        out[pair] = sc;
    }
}

extern "C" void kernel_launch(void* const* d_in, const int* in_sizes, int n_in,
                              void* d_out, int out_size, void* d_ws, size_t ws_size,
                              hipStream_t stream) {
    const int*   posdoc = (const int*)  d_in[0];
    const int*   negdoc = (const int*)  d_in[1];
    const int*   query  = (const int*)  d_in[2];
    const float* emb    = (const float*)d_in[4];
    const float* mus    = (const float*)d_in[5];
    const float* sigmas = (const float*)d_in[6];
    const float* Wv     = (const float*)d_in[7];
    const float* bv     = (const float*)d_in[8];
    float* out = (float*)d_out;

    const int V = in_sizes[4] / DD;          // 50000
    const size_t table_bytes = (size_t)V * KPAD;                     // 16 MB fp8
    const size_t part_bytes  = (size_t)512 * NCH * 12 * BQ * sizeof(float);

    if (ws_size >= table_bytes + part_bytes) {
        u8*    table = (u8*)d_ws;
        float* part  = (float*)((char*)d_ws + table_bytes);
        knrm_norm_table<<<dim3((V + 3) / 4), dim3(256), 0, stream>>>(emb, table, V);
        knrm_mfma<<<dim3(512 * NCH), dim3(256), 0, stream>>>(
            posdoc, negdoc, query, table, mus, sigmas, part);
        knrm_final<<<dim3(512), dim3(192), 0, stream>>>(part, Wv, bv, out, NCH);
    } else {
        float* part = (float*)d_ws;
        knrm_partial<<<dim3(512 * 4), dim3(256), 0, stream>>>(
            posdoc, negdoc, query, emb, mus, sigmas, part);
        knrm_final<<<dim3(512), dim3(192), 0, stream>>>(part, Wv, bv, out, 4);
    }
}